// Round 2
// baseline (2304.231 us; speedup 1.0000x reference)
//
#include <hip/hip_runtime.h>
#include <stdint.h>

#define NT   8192
#define DI   2048
#define DH   16384
#define DO   2048
#define KSEL 64
#define EPS_SEL 0.004f
#define BCAP 256

typedef _Float16 f16;
typedef f16  f16x8 __attribute__((ext_vector_type(8)));
typedef float f32x4 __attribute__((ext_vector_type(4)));
typedef unsigned short usx8 __attribute__((ext_vector_type(8)));

__device__ __forceinline__ unsigned short f2h_bits(float x){
  f16 h = (f16)x;
  union { f16 h; unsigned short u; } c; c.h = h; return c.u;
}
__device__ __forceinline__ float h_bits2f(unsigned short u){
  union { unsigned short u; f16 h; } c; c.u = u; return (float)c.h;
}

__device__ __forceinline__ void gload16(const void* g, void* lds){
  __builtin_amdgcn_global_load_lds(
    (const __attribute__((address_space(1))) void*)(uintptr_t)g,
    (__attribute__((address_space(3))) void*)(uint32_t)(uintptr_t)lds,
    16, 0, 0);
}

// ---------------- f32 -> f16 convert (vector8) ----------------
__global__ __launch_bounds__(256) void k_cvt(const float* __restrict__ in,
                                             unsigned short* __restrict__ out, int n8)
{
  int i = blockIdx.x*256 + threadIdx.x;
  if (i >= n8) return;
  const float4* p = (const float4*)in + (size_t)i*2;
  float4 a = p[0], b = p[1];
  union { f16 h[8]; usx8 u; } r;
  r.h[0]=(f16)a.x; r.h[1]=(f16)a.y; r.h[2]=(f16)a.z; r.h[3]=(f16)a.w;
  r.h[4]=(f16)b.x; r.h[5]=(f16)b.y; r.h[6]=(f16)b.z; r.h[7]=(f16)b.w;
  ((usx8*)out)[i] = r.u;
}

// ---------------- W_dec [DO][DH] f32 -> WdecT [DH][DO] f16 ----------------
__global__ __launch_bounds__(256) void k_transpose_cvt(const float* __restrict__ W,
                                                       unsigned short* __restrict__ WT)
{
  __shared__ unsigned short t[64][65];
  const int r0 = blockIdx.x*64;   // over DO
  const int c0 = blockIdx.y*64;   // over DH
  const int tid = threadIdx.x;
  const int q = tid >> 6, s = tid & 63;
#pragma unroll
  for (int i=0;i<16;i++){
    int r = q + i*4;
    t[r][s] = f2h_bits(W[(size_t)(r0+r)*DH + c0 + s]);
  }
  __syncthreads();
#pragma unroll
  for (int i=0;i<16;i++){
    int c = q + i*4;
    WT[(size_t)(c0+c)*DO + r0 + s] = t[s][c];
  }
}

// ---------------- f16 MFMA GEMM: C[M][N] = A[M][K] * B[N][K]^T + bias ----------------
// LDS layout per K-tile (BK=32): [row-group g (8)][kq (4)][row-in-group (16)] of
// 16B chunks. Achieved with linear global_load_lds dest + permuted per-lane global
// source (lane = kq*16 + row). Fragment ds_read_b128 is then 64 lanes over one
// contiguous 1KB region -> conflict-free.
template<bool F16OUT>
__global__ __launch_bounds__(256) void k_gemm(
    const unsigned short* __restrict__ A,
    const unsigned short* __restrict__ B,
    const float* __restrict__ bias1,
    const float* __restrict__ bias2,
    void* __restrict__ Cout,
    int M, int N, int Kd)
{
  __shared__ unsigned short lA[128*32];
  __shared__ unsigned short lB[128*32];
  const int tid  = threadIdx.x;
  const int lane = tid & 63;
  const int wv   = tid >> 6;
  const int bm   = blockIdx.x, bn = blockIdx.y;
  const int wm   = wv >> 1, wn = wv & 1;

  f32x4 acc[4][4];
#pragma unroll
  for (int m=0;m<4;m++)
#pragma unroll
    for (int n=0;n<4;n++) acc[m][n] = (f32x4){0.f,0.f,0.f,0.f};

  // staging source: lane = kq*16 + r  (r = row within 16-row group, kq = k-quad)
  const int r16 = lane & 15;
  const int kq4 = lane >> 4;
  const unsigned short* gA = A + (size_t)(bm*128 + wv*16 + r16)*Kd + kq4*8;
  const unsigned short* gB = B + (size_t)(bn*128 + wv*16 + r16)*Kd + kq4*8;
  // dest group bases (512 shorts = 1KB per group): A groups wv and wv+4
  unsigned short* lA0 = &lA[wv*512];
  unsigned short* lA1 = &lA[(wv+4)*512];
  unsigned short* lB0 = &lB[wv*512];
  unsigned short* lB1 = &lB[(wv+4)*512];

  for (int k0 = 0; k0 < Kd; k0 += 32) {
    gload16(gA + k0,                  lA0);
    gload16(gA + k0 + (size_t)64*Kd,  lA1);
    gload16(gB + k0,                  lB0);
    gload16(gB + k0 + (size_t)64*Kd,  lB1);
    __syncthreads();
    const int kq = lane >> 4;       // 0..3
    const int rr = lane & 15;
    f16x8 af[4], bf[4];
#pragma unroll
    for (int m=0;m<4;m++)
      af[m] = *(const f16x8*)&lA[(wm*4 + m)*512 + kq*128 + rr*8];
#pragma unroll
    for (int n=0;n<4;n++)
      bf[n] = *(const f16x8*)&lB[(wn*4 + n)*512 + kq*128 + rr*8];
#pragma unroll
    for (int m=0;m<4;m++)
#pragma unroll
      for (int n=0;n<4;n++)
        acc[m][n] = __builtin_amdgcn_mfma_f32_16x16x32_f16(af[m], bf[n], acc[m][n], 0, 0, 0);
    __syncthreads();
  }

  const int rowBase = bm*128 + wm*64 + ((lane>>4)<<2);
  const int colBase = bn*128 + wn*64 + (lane & 15);
#pragma unroll
  for (int n=0;n<4;n++) {
    const int col = colBase + n*16;
    float bs = bias1[col];
    if (bias2) bs += bias2[col];
#pragma unroll
    for (int m=0;m<4;m++) {
#pragma unroll
      for (int q=0;q<4;q++) {
        const int row = rowBase + m*16 + q;
        float v = acc[m][n][q] + bs;
        if (F16OUT) ((unsigned short*)Cout)[(size_t)row*N + col] = f2h_bits(v);
        else        ((float*)Cout)[(size_t)row*N + col] = v;
      }
    }
  }
}

// ---------------- exact top-64 per row ----------------
__global__ __launch_bounds__(256) void k_topk(
    const unsigned short* __restrict__ P,   // f16 preacts [NT][DH]
    const float* __restrict__ X,            // [NT][DI] f32
    const float* __restrict__ Wenc,         // [DH][DI] f32
    const float* __restrict__ benc,         // [DH]
    int*   __restrict__ candIdx,            // [NT][KSEL]
    float* __restrict__ candVal)
{
  __shared__ unsigned short row[DH];
  __shared__ unsigned int hist[256];
  __shared__ int inIdx[64];
  __shared__ int bandIdx[BCAP];
  __shared__ double bandVal[BCAP];
  __shared__ unsigned char bandUsed[BCAP];
  __shared__ int s_inCnt, s_bandCnt, s_bsel, s_cntAbove;
  __shared__ float s_T;

  const int r = blockIdx.x;
  const int tid = threadIdx.x;
  const unsigned short* Prow = P + (size_t)r*DH;

  for (int i=tid; i<DH/8; i+=256) ((usx8*)row)[i] = ((const usx8*)Prow)[i];
  hist[tid & 255] = 0;
  if (tid==0){ s_inCnt=0; s_bandCnt=0; }
  __syncthreads();

  // radix pass 1: high byte of order-mapped u16
  for (int i=tid;i<DH;i+=256){
    unsigned short b = row[i];
    unsigned short o = (b & 0x8000) ? (unsigned short)~b : (unsigned short)(b|0x8000);
    atomicAdd(&hist[o>>8], 1u);
  }
  __syncthreads();
  if (tid==0){
    int cum=0, bsel=0;
    for (int h=255; h>=0; h--){
      if (cum + (int)hist[h] >= KSEL){ bsel=h; break; }
      cum += hist[h];
    }
    s_bsel = bsel; s_cntAbove = cum;
  }
  __syncthreads();
  const int bsel = s_bsel; const int cntAbove = s_cntAbove;
  hist[tid & 255] = 0;
  __syncthreads();
  // radix pass 2: low byte within bucket
  for (int i=tid;i<DH;i+=256){
    unsigned short b = row[i];
    unsigned short o = (b & 0x8000) ? (unsigned short)~b : (unsigned short)(b|0x8000);
    if ((int)(o>>8)==bsel) atomicAdd(&hist[o&0xff],1u);
  }
  __syncthreads();
  if (tid==0){
    int cum = cntAbove, lsel = 0;
    for (int h=255; h>=0; h--){
      if (cum + (int)hist[h] >= KSEL){ lsel=h; break; }
      cum += hist[h];
    }
    unsigned short To = (unsigned short)((bsel<<8) | lsel);
    unsigned short tb = (To & 0x8000) ? (unsigned short)(To ^ 0x8000) : (unsigned short)~To;
    s_T = h_bits2f(tb);
  }
  __syncthreads();
  const float T = s_T;
  const float hiv = T + 2.0f*EPS_SEL, lov = T - 2.0f*EPS_SEL;

  for (int i=tid;i<DH;i+=256){
    float v = h_bits2f(row[i]);
    if (v > hiv){
      int p = atomicAdd(&s_inCnt,1);
      if (p < 64) inIdx[p] = i;
    } else if (v >= lov){
      int p = atomicAdd(&s_bandCnt,1);
      if (p < BCAP) bandIdx[p] = i;
    }
  }
  __syncthreads();
  const int m = s_inCnt < 64 ? s_inCnt : 64;
  const int B = s_bandCnt < BCAP ? s_bandCnt : BCAP;

  // exact f64 recompute for ambiguous band (from original f32 inputs)
  const int wv = tid>>6, lane = tid&63;
  const float* Xr = X + (size_t)r*DI;
  for (int b=wv; b<B; b+=4){
    const int j = bandIdx[b];
    const float* Wr = Wenc + (size_t)j*DI;
    double s = 0.0;
    for (int k=lane; k<DI; k+=64)
      s = fma((double)Xr[k], (double)Wr[k], s);
#pragma unroll
    for (int off=32; off>=1; off>>=1) s += __shfl_down(s, off);
    if (lane==0) bandVal[b] = s + (double)benc[j];
  }
  for (int i=tid;i<BCAP;i+=256) bandUsed[i]=0;

  int* ci = candIdx + (size_t)r*KSEL;
  float* cv = candVal + (size_t)r*KSEL;
  for (int t=tid; t<m; t+=256){
    int j = inIdx[t];
    ci[t]=j; cv[t]=h_bits2f(row[j]);
  }
  __syncthreads();
  if (tid==0){
    int need = KSEL - m;
    for (int t=0;t<need;t++){
      double best=-1e300; int bi=0;
      for (int b=0;b<B;b++)
        if (!bandUsed[b] && bandVal[b]>best){ best=bandVal[b]; bi=b; }
      bandUsed[bi]=1;
      ci[m+t]=bandIdx[bi]; cv[m+t]=(float)best;
    }
  }
}

// ---------------- sparse decode + loss partial ----------------
__global__ __launch_bounds__(256) void k_decode(
    float* __restrict__ outhat,              // [NT][DO], holds skip part
    const unsigned short* __restrict__ WdT,  // f16 [DH][DO]
    const int*   __restrict__ candIdx,
    const float* __restrict__ candVal,
    const float* __restrict__ target,
    float* __restrict__ lossPartial)
{
  __shared__ int   sIdx[KSEL];
  __shared__ float sVal[KSEL];
  __shared__ float wsum[4];
  const int r = blockIdx.x, tid = threadIdx.x;
  if (tid < KSEL){
    sIdx[tid]=candIdx[(size_t)r*KSEL+tid];
    float v=candVal[(size_t)r*KSEL+tid];
    sVal[tid] = v>0.f ? v : 0.f;
  }
  __syncthreads();
  float* orow = outhat + (size_t)r*DO;
  float a[8];
  {
    float4 v0 = *(const float4*)(orow + tid*8);
    float4 v1 = *(const float4*)(orow + tid*8 + 4);
    a[0]=v0.x;a[1]=v0.y;a[2]=v0.z;a[3]=v0.w;a[4]=v1.x;a[5]=v1.y;a[6]=v1.z;a[7]=v1.w;
  }
  for (int c=0;c<KSEL;c++){
    const float v = sVal[c];
    if (v==0.f) continue;
    const f16x8 w = *(const f16x8*)(WdT + (size_t)sIdx[c]*DO + tid*8);
#pragma unroll
    for (int j=0;j<8;j++) a[j] = fmaf(v, (float)w[j], a[j]);
  }
  const float* trow = target + (size_t)r*DO;
  float4 t0 = *(const float4*)(trow + tid*8);
  float4 t1 = *(const float4*)(trow + tid*8 + 4);
  float tt[8] = {t0.x,t0.y,t0.z,t0.w,t1.x,t1.y,t1.z,t1.w};
  float ls = 0.f;
#pragma unroll
  for (int j=0;j<8;j++){ float d = a[j]-tt[j]; ls = fmaf(d,d,ls); }
  {
    float4 v0 = {a[0],a[1],a[2],a[3]}, v1 = {a[4],a[5],a[6],a[7]};
    *(float4*)(orow + tid*8) = v0;
    *(float4*)(orow + tid*8 + 4) = v1;
  }
#pragma unroll
  for (int off=32; off>=1; off>>=1) ls += __shfl_down(ls, off);
  if ((tid&63)==0) wsum[tid>>6]=ls;
  __syncthreads();
  if (tid==0)
    lossPartial[r] = (wsum[0]+wsum[1]+wsum[2]+wsum[3]) * (1.0f/((float)NT*(float)DO));
}

__global__ __launch_bounds__(256) void k_lossreduce(const float* __restrict__ lp,
                                                    float* __restrict__ out)
{
  __shared__ double ws[4];
  double s=0.0;
  for (int i=threadIdx.x;i<NT;i+=256) s += (double)lp[i];
#pragma unroll
  for (int off=32; off>=1; off>>=1) s += __shfl_down(s, off);
  if ((threadIdx.x&63)==0) ws[threadIdx.x>>6]=s;
  __syncthreads();
  if (threadIdx.x==0) *out = (float)(ws[0]+ws[1]+ws[2]+ws[3]);
}

// ---------------- finalize h: zero + scatter ----------------
__global__ __launch_bounds__(256) void k_scatter(
    float* __restrict__ H, const int* __restrict__ candIdx, const float* __restrict__ candVal)
{
  const int r=blockIdx.x, tid=threadIdx.x;
  float* hr = H + (size_t)r*DH;
  const float4 z = {0.f,0.f,0.f,0.f};
#pragma unroll
  for (int i=0;i<16;i++) ((float4*)hr)[tid + i*256] = z;
  __syncthreads();
  if (tid<KSEL){
    float v = candVal[(size_t)r*KSEL+tid];
    hr[candIdx[(size_t)r*KSEL+tid]] = v>0.f ? v : 0.f;
  }
}

extern "C" void kernel_launch(void* const* d_in, const int* in_sizes, int n_in,
                              void* d_out, int out_size, void* d_ws, size_t ws_size,
                              hipStream_t stream)
{
  const float* X     = (const float*)d_in[0];
  const float* tgt   = (const float*)d_in[1];
  const float* Wenc  = (const float*)d_in[2];
  const float* benc  = (const float*)d_in[3];
  const float* Wdec  = (const float*)d_in[4];
  const float* bdec  = (const float*)d_in[5];
  const float* Wskip = (const float*)d_in[6];
  const float* bskip = (const float*)d_in[7];

  float* out     = (float*)d_out;
  float* outhat  = out;
  float* H       = out + (size_t)NT*DO;
  float* lossOut = out + (size_t)NT*DO + (size_t)NT*DH;

  // h-region scratch plan (dead until k_scatter):
  //   [0, 2^28)        : f16 pre-acts
  //   [2^28, ...)      : f16 copies of X, W_enc, W_skip, W_dec^T
  char* hb = (char*)H;
  unsigned short* P      = (unsigned short*)hb;
  char* U                = hb + (size_t)NT*DH*2;
  unsigned short* Xh     = (unsigned short*)U;
  unsigned short* Wench  = (unsigned short*)(U + (size_t)NT*DI*2);
  unsigned short* Wskiph = (unsigned short*)(U + (size_t)NT*DI*2 + (size_t)DH*DI*2);
  unsigned short* WdTh   = (unsigned short*)(U + (size_t)NT*DI*2 + (size_t)DH*DI*2 + (size_t)DO*DI*2);

  // ws: candidate lists must survive the h overwrite
  int*   candIdx    = (int*)d_ws;
  float* candVal    = (float*)((char*)d_ws + (size_t)NT*KSEL*4);
  float* lossPartial= (float*)((char*)d_ws + (size_t)NT*KSEL*8);

  k_cvt<<<NT*DI/8/256, 256, 0, stream>>>(X, Xh, NT*DI/8);
  k_cvt<<<DH*DI/8/256, 256, 0, stream>>>(Wenc, Wench, DH*DI/8);
  k_cvt<<<DO*DI/8/256, 256, 0, stream>>>(Wskip, Wskiph, DO*DI/8);
  k_transpose_cvt<<<dim3(DO/64, DH/64), 256, 0, stream>>>(Wdec, WdTh);

  k_gemm<true ><<<dim3(NT/128, DH/128), 256, 0, stream>>>(Xh, Wench, benc, nullptr, (void*)P, NT, DH, DI);
  k_topk<<<NT, 256, 0, stream>>>(P, X, Wenc, benc, candIdx, candVal);
  k_gemm<false><<<dim3(NT/128, DO/128), 256, 0, stream>>>(Xh, Wskiph, bdec, bskip, (void*)outhat, NT, DO, DI);
  k_decode<<<NT, 256, 0, stream>>>(outhat, WdTh, candIdx, candVal, tgt, lossPartial);
  k_lossreduce<<<1, 256, 0, stream>>>(lossPartial, lossOut);
  k_scatter<<<NT, 256, 0, stream>>>(H, candIdx, candVal);
}

// Round 3
// 1996.312 us; speedup vs baseline: 1.1542x; 1.1542x over previous
//
#include <hip/hip_runtime.h>
#include <stdint.h>

#define NT   8192
#define DI   2048
#define DH   16384
#define DO   2048
#define KSEL 64
#define EPS_SEL 0.004f
#define BCAP 256

typedef _Float16 f16;
typedef f16  f16x8 __attribute__((ext_vector_type(8)));
typedef float f32x4 __attribute__((ext_vector_type(4)));
typedef unsigned short usx8 __attribute__((ext_vector_type(8)));

__device__ __forceinline__ unsigned short f2h_bits(float x){
  f16 h = (f16)x;
  union { f16 h; unsigned short u; } c; c.h = h; return c.u;
}
__device__ __forceinline__ float h_bits2f(unsigned short u){
  union { unsigned short u; f16 h; } c; c.u = u; return (float)c.h;
}

__device__ __forceinline__ void gload16(const void* g, void* lds){
  __builtin_amdgcn_global_load_lds(
    (const __attribute__((address_space(1))) void*)(uintptr_t)g,
    (__attribute__((address_space(3))) void*)(uint32_t)(uintptr_t)lds,
    16, 0, 0);
}

// ---------------- f32 -> f16 convert (vector8) ----------------
__global__ __launch_bounds__(256) void k_cvt(const float* __restrict__ in,
                                             unsigned short* __restrict__ out, int n8)
{
  int i = blockIdx.x*256 + threadIdx.x;
  if (i >= n8) return;
  const float4* p = (const float4*)in + (size_t)i*2;
  float4 a = p[0], b = p[1];
  union { f16 h[8]; usx8 u; } r;
  r.h[0]=(f16)a.x; r.h[1]=(f16)a.y; r.h[2]=(f16)a.z; r.h[3]=(f16)a.w;
  r.h[4]=(f16)b.x; r.h[5]=(f16)b.y; r.h[6]=(f16)b.z; r.h[7]=(f16)b.w;
  ((usx8*)out)[i] = r.u;
}

// ---------------- W_dec [DO][DH] f32 -> WdecT [DH][DO] f16 ----------------
__global__ __launch_bounds__(256) void k_transpose_cvt(const float* __restrict__ W,
                                                       unsigned short* __restrict__ WT)
{
  __shared__ unsigned short t[64][65];
  const int r0 = blockIdx.x*64;   // over DO
  const int c0 = blockIdx.y*64;   // over DH
  const int tid = threadIdx.x;
  const int q = tid >> 6, s = tid & 63;
#pragma unroll
  for (int i=0;i<16;i++){
    int r = q + i*4;
    t[r][s] = f2h_bits(W[(size_t)(r0+r)*DH + c0 + s]);
  }
  __syncthreads();
#pragma unroll
  for (int i=0;i<16;i++){
    int c = q + i*4;
    WT[(size_t)(c0+c)*DO + r0 + s] = t[s][c];
  }
}

// ---------------- f16 MFMA GEMM: C[M][N] = A[M][K] * B[N][K]^T + bias ----------------
// LDS: linear DMA dest; involution chunk swizzle applied on BOTH the per-lane
// global source (kq ^= (lane>>4)&3, keeps each 4-lane quad inside one contiguous
// 64B global segment) and the ds_read address (kq ^= (rr>>2)&3). Bank-quad index
// = 4*(rr&1) + kq^t(rr) covers all 8 groups with 2 lanes each -> conflict-free.
template<bool F16OUT>
__global__ __launch_bounds__(256) void k_gemm(
    const unsigned short* __restrict__ A,
    const unsigned short* __restrict__ B,
    const float* __restrict__ bias1,
    const float* __restrict__ bias2,
    void* __restrict__ Cout,
    int M, int N, int Kd)
{
  __shared__ unsigned short lA[128*32];
  __shared__ unsigned short lB[128*32];
  const int tid  = threadIdx.x;
  const int lane = tid & 63;
  const int wv   = tid >> 6;
  const int bm   = blockIdx.x, bn = blockIdx.y;
  const int wm   = wv >> 1, wn = wv & 1;

  f32x4 acc[4][4];
#pragma unroll
  for (int m=0;m<4;m++)
#pragma unroll
    for (int n=0;n<4;n++) acc[m][n] = (f32x4){0.f,0.f,0.f,0.f};

  // staging source: quad g = lane>>2 reads row g; within-quad k-chunk order
  // XOR-permuted by t(g) = (lane>>4)&3 (involution, matches read-side swizzle)
  const int lr  = lane >> 2;                       // local row 0..15
  const int kqs = (lane & 3) ^ ((lane >> 4) & 3);  // swizzled source k-quad
  const unsigned short* gA = A + (size_t)(bm*128 + wv*16 + lr)*Kd + kqs*8;
  const unsigned short* gB = B + (size_t)(bn*128 + wv*16 + lr)*Kd + kqs*8;
  unsigned short* lA0 = &lA[wv*512];
  unsigned short* lA1 = &lA[(wv+4)*512];
  unsigned short* lB0 = &lB[wv*512];
  unsigned short* lB1 = &lB[(wv+4)*512];

  for (int k0 = 0; k0 < Kd; k0 += 32) {
    gload16(gA + k0,                  lA0);
    gload16(gA + k0 + (size_t)64*Kd,  lA1);
    gload16(gB + k0,                  lB0);
    gload16(gB + k0 + (size_t)64*Kd,  lB1);
    __syncthreads();
    const int kq = lane >> 4;       // 0..3
    const int rr = lane & 15;
    const int kqx = kq ^ ((rr >> 2) & 3);  // read-side swizzle (same involution)
    f16x8 af[4], bf[4];
#pragma unroll
    for (int m=0;m<4;m++)
      af[m] = *(const f16x8*)&lA[(wm*64 + m*16 + rr)*32 + kqx*8];
#pragma unroll
    for (int n=0;n<4;n++)
      bf[n] = *(const f16x8*)&lB[(wn*64 + n*16 + rr)*32 + kqx*8];
#pragma unroll
    for (int m=0;m<4;m++)
#pragma unroll
      for (int n=0;n<4;n++)
        acc[m][n] = __builtin_amdgcn_mfma_f32_16x16x32_f16(af[m], bf[n], acc[m][n], 0, 0, 0);
    __syncthreads();
  }

  const int rowBase = bm*128 + wm*64 + ((lane>>4)<<2);
  const int colBase = bn*128 + wn*64 + (lane & 15);
#pragma unroll
  for (int n=0;n<4;n++) {
    const int col = colBase + n*16;
    float bs = bias1[col];
    if (bias2) bs += bias2[col];
#pragma unroll
    for (int m=0;m<4;m++) {
#pragma unroll
      for (int q=0;q<4;q++) {
        const int row = rowBase + m*16 + q;
        float v = acc[m][n][q] + bs;
        if (F16OUT) ((unsigned short*)Cout)[(size_t)row*N + col] = f2h_bits(v);
        else        ((float*)Cout)[(size_t)row*N + col] = v;
      }
    }
  }
}

// ---------------- exact top-64 per row ----------------
__global__ __launch_bounds__(256) void k_topk(
    const unsigned short* __restrict__ P,   // f16 preacts [NT][DH]
    const float* __restrict__ X,            // [NT][DI] f32
    const float* __restrict__ Wenc,         // [DH][DI] f32
    const float* __restrict__ benc,         // [DH]
    int*   __restrict__ candIdx,            // [NT][KSEL]
    float* __restrict__ candVal)
{
  __shared__ unsigned short row[DH];
  __shared__ unsigned int hist[256];
  __shared__ int inIdx[64];
  __shared__ int bandIdx[BCAP];
  __shared__ double bandVal[BCAP];
  __shared__ unsigned char bandUsed[BCAP];
  __shared__ int s_inCnt, s_bandCnt, s_bsel, s_cntAbove;
  __shared__ float s_T;

  const int r = blockIdx.x;
  const int tid = threadIdx.x;
  const unsigned short* Prow = P + (size_t)r*DH;

  for (int i=tid; i<DH/8; i+=256) ((usx8*)row)[i] = ((const usx8*)Prow)[i];
  hist[tid & 255] = 0;
  if (tid==0){ s_inCnt=0; s_bandCnt=0; }
  __syncthreads();

  // radix pass 1: high byte of order-mapped u16
  for (int i=tid;i<DH;i+=256){
    unsigned short b = row[i];
    unsigned short o = (b & 0x8000) ? (unsigned short)~b : (unsigned short)(b|0x8000);
    atomicAdd(&hist[o>>8], 1u);
  }
  __syncthreads();
  if (tid==0){
    int cum=0, bsel=0;
    for (int h=255; h>=0; h--){
      if (cum + (int)hist[h] >= KSEL){ bsel=h; break; }
      cum += hist[h];
    }
    s_bsel = bsel; s_cntAbove = cum;
  }
  __syncthreads();
  const int bsel = s_bsel; const int cntAbove = s_cntAbove;
  hist[tid & 255] = 0;
  __syncthreads();
  // radix pass 2: low byte within bucket
  for (int i=tid;i<DH;i+=256){
    unsigned short b = row[i];
    unsigned short o = (b & 0x8000) ? (unsigned short)~b : (unsigned short)(b|0x8000);
    if ((int)(o>>8)==bsel) atomicAdd(&hist[o&0xff],1u);
  }
  __syncthreads();
  if (tid==0){
    int cum = cntAbove, lsel = 0;
    for (int h=255; h>=0; h--){
      if (cum + (int)hist[h] >= KSEL){ lsel=h; break; }
      cum += hist[h];
    }
    unsigned short To = (unsigned short)((bsel<<8) | lsel);
    unsigned short tb = (To & 0x8000) ? (unsigned short)(To ^ 0x8000) : (unsigned short)~To;
    s_T = h_bits2f(tb);
  }
  __syncthreads();
  const float T = s_T;
  const float hiv = T + 2.0f*EPS_SEL, lov = T - 2.0f*EPS_SEL;

  for (int i=tid;i<DH;i+=256){
    float v = h_bits2f(row[i]);
    if (v > hiv){
      int p = atomicAdd(&s_inCnt,1);
      if (p < 64) inIdx[p] = i;
    } else if (v >= lov){
      int p = atomicAdd(&s_bandCnt,1);
      if (p < BCAP) bandIdx[p] = i;
    }
  }
  __syncthreads();
  const int m = s_inCnt < 64 ? s_inCnt : 64;
  const int B = s_bandCnt < BCAP ? s_bandCnt : BCAP;

  // exact f64 recompute for ambiguous band (from original f32 inputs)
  const int wv = tid>>6, lane = tid&63;
  const float* Xr = X + (size_t)r*DI;
  for (int b=wv; b<B; b+=4){
    const int j = bandIdx[b];
    const float* Wr = Wenc + (size_t)j*DI;
    double s = 0.0;
    for (int k=lane; k<DI; k+=64)
      s = fma((double)Xr[k], (double)Wr[k], s);
#pragma unroll
    for (int off=32; off>=1; off>>=1) s += __shfl_down(s, off);
    if (lane==0) bandVal[b] = s + (double)benc[j];
  }
  for (int i=tid;i<BCAP;i+=256) bandUsed[i]=0;

  int* ci = candIdx + (size_t)r*KSEL;
  float* cv = candVal + (size_t)r*KSEL;
  for (int t=tid; t<m; t+=256){
    int j = inIdx[t];
    ci[t]=j; cv[t]=h_bits2f(row[j]);
  }
  __syncthreads();
  if (tid==0){
    int need = KSEL - m;
    for (int t=0;t<need;t++){
      double best=-1e300; int bi=0;
      for (int b=0;b<B;b++)
        if (!bandUsed[b] && bandVal[b]>best){ best=bandVal[b]; bi=b; }
      bandUsed[bi]=1;
      ci[m+t]=bandIdx[bi]; cv[m+t]=(float)best;
    }
  }
}

// ---------------- sparse decode + loss partial ----------------
__global__ __launch_bounds__(256) void k_decode(
    float* __restrict__ outhat,              // [NT][DO], holds skip part
    const unsigned short* __restrict__ WdT,  // f16 [DH][DO]
    const int*   __restrict__ candIdx,
    const float* __restrict__ candVal,
    const float* __restrict__ target,
    float* __restrict__ lossPartial)
{
  __shared__ int   sIdx[KSEL];
  __shared__ float sVal[KSEL];
  __shared__ float wsum[4];
  const int r = blockIdx.x, tid = threadIdx.x;
  if (tid < KSEL){
    sIdx[tid]=candIdx[(size_t)r*KSEL+tid];
    float v=candVal[(size_t)r*KSEL+tid];
    sVal[tid] = v>0.f ? v : 0.f;
  }
  __syncthreads();
  float* orow = outhat + (size_t)r*DO;
  float a[8];
  {
    float4 v0 = *(const float4*)(orow + tid*8);
    float4 v1 = *(const float4*)(orow + tid*8 + 4);
    a[0]=v0.x;a[1]=v0.y;a[2]=v0.z;a[3]=v0.w;a[4]=v1.x;a[5]=v1.y;a[6]=v1.z;a[7]=v1.w;
  }
  for (int c=0;c<KSEL;c++){
    const float v = sVal[c];
    if (v==0.f) continue;
    const f16x8 w = *(const f16x8*)(WdT + (size_t)sIdx[c]*DO + tid*8);
#pragma unroll
    for (int j=0;j<8;j++) a[j] = fmaf(v, (float)w[j], a[j]);
  }
  const float* trow = target + (size_t)r*DO;
  float4 t0 = *(const float4*)(trow + tid*8);
  float4 t1 = *(const float4*)(trow + tid*8 + 4);
  float tt[8] = {t0.x,t0.y,t0.z,t0.w,t1.x,t1.y,t1.z,t1.w};
  float ls = 0.f;
#pragma unroll
  for (int j=0;j<8;j++){ float d = a[j]-tt[j]; ls = fmaf(d,d,ls); }
  {
    float4 v0 = {a[0],a[1],a[2],a[3]}, v1 = {a[4],a[5],a[6],a[7]};
    *(float4*)(orow + tid*8) = v0;
    *(float4*)(orow + tid*8 + 4) = v1;
  }
#pragma unroll
  for (int off=32; off>=1; off>>=1) ls += __shfl_down(ls, off);
  if ((tid&63)==0) wsum[tid>>6]=ls;
  __syncthreads();
  if (tid==0)
    lossPartial[r] = (wsum[0]+wsum[1]+wsum[2]+wsum[3]) * (1.0f/((float)NT*(float)DO));
}

__global__ __launch_bounds__(256) void k_lossreduce(const float* __restrict__ lp,
                                                    float* __restrict__ out)
{
  __shared__ double ws[4];
  double s=0.0;
  for (int i=threadIdx.x;i<NT;i+=256) s += (double)lp[i];
#pragma unroll
  for (int off=32; off>=1; off>>=1) s += __shfl_down(s, off);
  if ((threadIdx.x&63)==0) ws[threadIdx.x>>6]=s;
  __syncthreads();
  if (threadIdx.x==0) *out = (float)(ws[0]+ws[1]+ws[2]+ws[3]);
}

// ---------------- finalize h: zero + scatter ----------------
__global__ __launch_bounds__(256) void k_scatter(
    float* __restrict__ H, const int* __restrict__ candIdx, const float* __restrict__ candVal)
{
  const int r=blockIdx.x, tid=threadIdx.x;
  float* hr = H + (size_t)r*DH;
  const float4 z = {0.f,0.f,0.f,0.f};
#pragma unroll
  for (int i=0;i<16;i++) ((float4*)hr)[tid + i*256] = z;
  __syncthreads();
  if (tid<KSEL){
    float v = candVal[(size_t)r*KSEL+tid];
    hr[candIdx[(size_t)r*KSEL+tid]] = v>0.f ? v : 0.f;
  }
}

extern "C" void kernel_launch(void* const* d_in, const int* in_sizes, int n_in,
                              void* d_out, int out_size, void* d_ws, size_t ws_size,
                              hipStream_t stream)
{
  const float* X     = (const float*)d_in[0];
  const float* tgt   = (const float*)d_in[1];
  const float* Wenc  = (const float*)d_in[2];
  const float* benc  = (const float*)d_in[3];
  const float* Wdec  = (const float*)d_in[4];
  const float* bdec  = (const float*)d_in[5];
  const float* Wskip = (const float*)d_in[6];
  const float* bskip = (const float*)d_in[7];

  float* out     = (float*)d_out;
  float* outhat  = out;
  float* H       = out + (size_t)NT*DO;
  float* lossOut = out + (size_t)NT*DO + (size_t)NT*DH;

  // h-region scratch plan (dead until k_scatter):
  //   [0, 2^28)        : f16 pre-acts
  //   [2^28, ...)      : f16 copies of X, W_enc, W_skip, W_dec^T
  char* hb = (char*)H;
  unsigned short* P      = (unsigned short*)hb;
  char* U                = hb + (size_t)NT*DH*2;
  unsigned short* Xh     = (unsigned short*)U;
  unsigned short* Wench  = (unsigned short*)(U + (size_t)NT*DI*2);
  unsigned short* Wskiph = (unsigned short*)(U + (size_t)NT*DI*2 + (size_t)DH*DI*2);
  unsigned short* WdTh   = (unsigned short*)(U + (size_t)NT*DI*2 + (size_t)DH*DI*2 + (size_t)DO*DI*2);

  // ws: candidate lists must survive the h overwrite
  int*   candIdx    = (int*)d_ws;
  float* candVal    = (float*)((char*)d_ws + (size_t)NT*KSEL*4);
  float* lossPartial= (float*)((char*)d_ws + (size_t)NT*KSEL*8);

  k_cvt<<<NT*DI/8/256, 256, 0, stream>>>(X, Xh, NT*DI/8);
  k_cvt<<<DH*DI/8/256, 256, 0, stream>>>(Wenc, Wench, DH*DI/8);
  k_cvt<<<DO*DI/8/256, 256, 0, stream>>>(Wskip, Wskiph, DO*DI/8);
  k_transpose_cvt<<<dim3(DO/64, DH/64), 256, 0, stream>>>(Wdec, WdTh);

  k_gemm<true ><<<dim3(NT/128, DH/128), 256, 0, stream>>>(Xh, Wench, benc, nullptr, (void*)P, NT, DH, DI);
  k_topk<<<NT, 256, 0, stream>>>(P, X, Wenc, benc, candIdx, candVal);
  k_gemm<false><<<dim3(NT/128, DO/128), 256, 0, stream>>>(Xh, Wskiph, bdec, bskip, (void*)outhat, NT, DO, DI);
  k_decode<<<NT, 256, 0, stream>>>(outhat, WdTh, candIdx, candVal, tgt, lossPartial);
  k_lossreduce<<<1, 256, 0, stream>>>(lossPartial, lossOut);
  k_scatter<<<NT, 256, 0, stream>>>(H, candIdx, candVal);
}

// Round 4
// 1916.755 us; speedup vs baseline: 1.2022x; 1.0415x over previous
//
#include <hip/hip_runtime.h>
#include <stdint.h>

#define NT   8192
#define DI   2048
#define DH   16384
#define DO   2048
#define KSEL 64
#define EPS_SEL 0.004f
#define BCAP 256
#define KSTEPS 64   // K=2048 / BK=32 for both GEMMs

typedef _Float16 f16;
typedef f16  f16x8 __attribute__((ext_vector_type(8)));
typedef float f32x4 __attribute__((ext_vector_type(4)));
typedef unsigned short usx8 __attribute__((ext_vector_type(8)));

__device__ __forceinline__ unsigned short f2h_bits(float x){
  f16 h = (f16)x;
  union { f16 h; unsigned short u; } c; c.h = h; return c.u;
}
__device__ __forceinline__ float h_bits2f(unsigned short u){
  union { unsigned short u; f16 h; } c; c.u = u; return (float)c.h;
}

__device__ __forceinline__ void gload16(const void* g, void* lds){
  __builtin_amdgcn_global_load_lds(
    (const __attribute__((address_space(1))) void*)(uintptr_t)g,
    (__attribute__((address_space(3))) void*)(uint32_t)(uintptr_t)lds,
    16, 0, 0);
}

// ---------------- f32 -> f16 convert (vector8) ----------------
__global__ __launch_bounds__(256) void k_cvt(const float* __restrict__ in,
                                             unsigned short* __restrict__ out, int n8)
{
  int i = blockIdx.x*256 + threadIdx.x;
  if (i >= n8) return;
  const float4* p = (const float4*)in + (size_t)i*2;
  float4 a = p[0], b = p[1];
  union { f16 h[8]; usx8 u; } r;
  r.h[0]=(f16)a.x; r.h[1]=(f16)a.y; r.h[2]=(f16)a.z; r.h[3]=(f16)a.w;
  r.h[4]=(f16)b.x; r.h[5]=(f16)b.y; r.h[6]=(f16)b.z; r.h[7]=(f16)b.w;
  ((usx8*)out)[i] = r.u;
}

// ---------------- W_dec [DO][DH] f32 -> WdecT [DH][DO] f16 ----------------
__global__ __launch_bounds__(256) void k_transpose_cvt(const float* __restrict__ W,
                                                       unsigned short* __restrict__ WT)
{
  __shared__ unsigned short t[64][65];
  const int r0 = blockIdx.x*64;   // over DO
  const int c0 = blockIdx.y*64;   // over DH
  const int tid = threadIdx.x;
  const int q = tid >> 6, s = tid & 63;
#pragma unroll
  for (int i=0;i<16;i++){
    int r = q + i*4;
    t[r][s] = f2h_bits(W[(size_t)(r0+r)*DH + c0 + s]);
  }
  __syncthreads();
#pragma unroll
  for (int i=0;i<16;i++){
    int c = q + i*4;
    WT[(size_t)(c0+c)*DO + r0 + s] = t[s][c];
  }
}

// ---------------- f16 MFMA GEMM: C[M][N] = A[M][K] * B[N][K]^T + bias ----------------
// 2-phase double-buffered pipeline (T3-minimum, m248v2): per K-step
//   STAGE(next tile -> other buffer); ds_read+MFMA(current); __syncthreads()
// Static buffer indices (rule #20). One barrier per K-step; the sync's vmcnt(0)
// drains loads issued a full compute-phase earlier. XCD-aware bijective block
// swizzle (T1, nwg%8==0): each XCD owns contiguous bm-bands (A-panel = 4MB = L2).
template<bool F16OUT>
__global__ __launch_bounds__(256) void k_gemm(
    const unsigned short* __restrict__ A,
    const unsigned short* __restrict__ B,
    const float* __restrict__ bias1,
    const float* __restrict__ bias2,
    void* __restrict__ Cout,
    int N, int Kd, int gridN)
{
  __shared__ unsigned short lA[2][128*32];
  __shared__ unsigned short lB[2][128*32];
  const int tid  = threadIdx.x;
  const int lane = tid & 63;
  const int wv   = tid >> 6;

  // XCD swizzle: hardware XCD = blockIdx.x % 8; give each XCD a contiguous
  // logical range. nwg % 8 == 0 for both GEMMs (8192, 1024).
  const int nwg = gridDim.x;
  const int cpx = nwg >> 3;
  const int swz = (blockIdx.x & 7) * cpx + (blockIdx.x >> 3);
  const int bm  = swz / gridN;      // bm-major: consecutive logical ids share A panel
  const int bn  = swz % gridN;

  const int wm   = wv >> 1, wn = wv & 1;

  f32x4 acc[4][4];
#pragma unroll
  for (int m=0;m<4;m++)
#pragma unroll
    for (int n=0;n<4;n++) acc[m][n] = (f32x4){0.f,0.f,0.f,0.f};

  // staging source (R0 layout): quad = one row's 64B, 16 rows per wave-issue
  const int lr  = lane >> 2;         // local row 0..15
  const int kq4 = lane & 3;          // 16B chunk within row
  const unsigned short* gA = A + (size_t)(bm*128 + wv*16 + lr)*Kd + kq4*8;
  const unsigned short* gB = B + (size_t)(bn*128 + wv*16 + lr)*Kd + kq4*8;

#define STAGE(BUF, KS) do { \
    const int _ko = (KS)*32; \
    gload16(gA + _ko,                  &lA[BUF][wv*512]); \
    gload16(gA + _ko + (size_t)64*Kd,  &lA[BUF][2048 + wv*512]); \
    gload16(gB + _ko,                  &lB[BUF][wv*512]); \
    gload16(gB + _ko + (size_t)64*Kd,  &lB[BUF][2048 + wv*512]); \
  } while(0)

#define COMPUTE(BUF) do { \
    const int kq = (lane >> 4) * 8; \
    const int rr = lane & 15; \
    f16x8 af[4], bf[4]; \
    _Pragma("unroll") \
    for (int m=0;m<4;m++) \
      af[m] = *(const f16x8*)&lA[BUF][(wm*64 + m*16 + rr)*32 + kq]; \
    _Pragma("unroll") \
    for (int n=0;n<4;n++) \
      bf[n] = *(const f16x8*)&lB[BUF][(wn*64 + n*16 + rr)*32 + kq]; \
    _Pragma("unroll") \
    for (int m=0;m<4;m++) \
      _Pragma("unroll") \
      for (int n=0;n<4;n++) \
        acc[m][n] = __builtin_amdgcn_mfma_f32_16x16x32_f16(af[m], bf[n], acc[m][n], 0, 0, 0); \
  } while(0)

  STAGE(0, 0);
  __syncthreads();
  for (int e = 0; e < KSTEPS-2; e += 2) {
    STAGE(1, e+1); COMPUTE(0); __syncthreads();
    STAGE(0, e+2); COMPUTE(1); __syncthreads();
  }
  STAGE(1, KSTEPS-1); COMPUTE(0); __syncthreads();
  COMPUTE(1);

#undef STAGE
#undef COMPUTE

  const int rowBase = bm*128 + wm*64 + ((lane>>4)<<2);
  const int colBase = bn*128 + wn*64 + (lane & 15);
#pragma unroll
  for (int n=0;n<4;n++) {
    const int col = colBase + n*16;
    float bs = bias1[col];
    if (bias2) bs += bias2[col];
#pragma unroll
    for (int m=0;m<4;m++) {
#pragma unroll
      for (int q=0;q<4;q++) {
        const int row = rowBase + m*16 + q;
        float v = acc[m][n][q] + bs;
        if (F16OUT) ((unsigned short*)Cout)[(size_t)row*N + col] = f2h_bits(v);
        else        ((float*)Cout)[(size_t)row*N + col] = v;
      }
    }
  }
}

// ---------------- exact top-64 per row ----------------
__global__ __launch_bounds__(256) void k_topk(
    const unsigned short* __restrict__ P,   // f16 preacts [NT][DH]
    const float* __restrict__ X,            // [NT][DI] f32
    const float* __restrict__ Wenc,         // [DH][DI] f32
    const float* __restrict__ benc,         // [DH]
    int*   __restrict__ candIdx,            // [NT][KSEL]
    float* __restrict__ candVal)
{
  __shared__ unsigned short row[DH];
  __shared__ unsigned int hist[256];
  __shared__ int inIdx[64];
  __shared__ int bandIdx[BCAP];
  __shared__ double bandVal[BCAP];
  __shared__ unsigned char bandUsed[BCAP];
  __shared__ int s_inCnt, s_bandCnt, s_bsel, s_cntAbove;
  __shared__ float s_T;

  const int r = blockIdx.x;
  const int tid = threadIdx.x;
  const unsigned short* Prow = P + (size_t)r*DH;

  for (int i=tid; i<DH/8; i+=256) ((usx8*)row)[i] = ((const usx8*)Prow)[i];
  hist[tid & 255] = 0;
  if (tid==0){ s_inCnt=0; s_bandCnt=0; }
  __syncthreads();

  // radix pass 1: high byte of order-mapped u16
  for (int i=tid;i<DH;i+=256){
    unsigned short b = row[i];
    unsigned short o = (b & 0x8000) ? (unsigned short)~b : (unsigned short)(b|0x8000);
    atomicAdd(&hist[o>>8], 1u);
  }
  __syncthreads();
  if (tid==0){
    int cum=0, bsel=0;
    for (int h=255; h>=0; h--){
      if (cum + (int)hist[h] >= KSEL){ bsel=h; break; }
      cum += hist[h];
    }
    s_bsel = bsel; s_cntAbove = cum;
  }
  __syncthreads();
  const int bsel = s_bsel; const int cntAbove = s_cntAbove;
  hist[tid & 255] = 0;
  __syncthreads();
  // radix pass 2: low byte within bucket
  for (int i=tid;i<DH;i+=256){
    unsigned short b = row[i];
    unsigned short o = (b & 0x8000) ? (unsigned short)~b : (unsigned short)(b|0x8000);
    if ((int)(o>>8)==bsel) atomicAdd(&hist[o&0xff],1u);
  }
  __syncthreads();
  if (tid==0){
    int cum = cntAbove, lsel = 0;
    for (int h=255; h>=0; h--){
      if (cum + (int)hist[h] >= KSEL){ lsel=h; break; }
      cum += hist[h];
    }
    unsigned short To = (unsigned short)((bsel<<8) | lsel);
    unsigned short tb = (To & 0x8000) ? (unsigned short)(To ^ 0x8000) : (unsigned short)~To;
    s_T = h_bits2f(tb);
  }
  __syncthreads();
  const float T = s_T;
  const float hiv = T + 2.0f*EPS_SEL, lov = T - 2.0f*EPS_SEL;

  for (int i=tid;i<DH;i+=256){
    float v = h_bits2f(row[i]);
    if (v > hiv){
      int p = atomicAdd(&s_inCnt,1);
      if (p < 64) inIdx[p] = i;
    } else if (v >= lov){
      int p = atomicAdd(&s_bandCnt,1);
      if (p < BCAP) bandIdx[p] = i;
    }
  }
  __syncthreads();
  const int m = s_inCnt < 64 ? s_inCnt : 64;
  const int B = s_bandCnt < BCAP ? s_bandCnt : BCAP;

  // exact f64 recompute for ambiguous band (from original f32 inputs)
  const int wv = tid>>6, lane = tid&63;
  const float* Xr = X + (size_t)r*DI;
  for (int b=wv; b<B; b+=4){
    const int j = bandIdx[b];
    const float* Wr = Wenc + (size_t)j*DI;
    double s = 0.0;
    for (int k=lane; k<DI; k+=64)
      s = fma((double)Xr[k], (double)Wr[k], s);
#pragma unroll
    for (int off=32; off>=1; off>>=1) s += __shfl_down(s, off);
    if (lane==0) bandVal[b] = s + (double)benc[j];
  }
  for (int i=tid;i<BCAP;i+=256) bandUsed[i]=0;

  int* ci = candIdx + (size_t)r*KSEL;
  float* cv = candVal + (size_t)r*KSEL;
  for (int t=tid; t<m; t+=256){
    int j = inIdx[t];
    ci[t]=j; cv[t]=h_bits2f(row[j]);
  }
  __syncthreads();
  if (tid==0){
    int need = KSEL - m;
    for (int t=0;t<need;t++){
      double best=-1e300; int bi=0;
      for (int b=0;b<B;b++)
        if (!bandUsed[b] && bandVal[b]>best){ best=bandVal[b]; bi=b; }
      bandUsed[bi]=1;
      ci[m+t]=bandIdx[bi]; cv[m+t]=(float)best;
    }
  }
}

// ---------------- sparse decode + loss partial ----------------
__global__ __launch_bounds__(256) void k_decode(
    float* __restrict__ outhat,              // [NT][DO], holds skip part
    const unsigned short* __restrict__ WdT,  // f16 [DH][DO]
    const int*   __restrict__ candIdx,
    const float* __restrict__ candVal,
    const float* __restrict__ target,
    float* __restrict__ lossPartial)
{
  __shared__ int   sIdx[KSEL];
  __shared__ float sVal[KSEL];
  __shared__ float wsum[4];
  const int r = blockIdx.x, tid = threadIdx.x;
  if (tid < KSEL){
    sIdx[tid]=candIdx[(size_t)r*KSEL+tid];
    float v=candVal[(size_t)r*KSEL+tid];
    sVal[tid] = v>0.f ? v : 0.f;
  }
  __syncthreads();
  float* orow = outhat + (size_t)r*DO;
  float a[8];
  {
    float4 v0 = *(const float4*)(orow + tid*8);
    float4 v1 = *(const float4*)(orow + tid*8 + 4);
    a[0]=v0.x;a[1]=v0.y;a[2]=v0.z;a[3]=v0.w;a[4]=v1.x;a[5]=v1.y;a[6]=v1.z;a[7]=v1.w;
  }
  for (int c=0;c<KSEL;c++){
    const float v = sVal[c];
    if (v==0.f) continue;
    const f16x8 w = *(const f16x8*)(WdT + (size_t)sIdx[c]*DO + tid*8);
#pragma unroll
    for (int j=0;j<8;j++) a[j] = fmaf(v, (float)w[j], a[j]);
  }
  const float* trow = target + (size_t)r*DO;
  float4 t0 = *(const float4*)(trow + tid*8);
  float4 t1 = *(const float4*)(trow + tid*8 + 4);
  float tt[8] = {t0.x,t0.y,t0.z,t0.w,t1.x,t1.y,t1.z,t1.w};
  float ls = 0.f;
#pragma unroll
  for (int j=0;j<8;j++){ float d = a[j]-tt[j]; ls = fmaf(d,d,ls); }
  {
    float4 v0 = {a[0],a[1],a[2],a[3]}, v1 = {a[4],a[5],a[6],a[7]};
    *(float4*)(orow + tid*8) = v0;
    *(float4*)(orow + tid*8 + 4) = v1;
  }
#pragma unroll
  for (int off=32; off>=1; off>>=1) ls += __shfl_down(ls, off);
  if ((tid&63)==0) wsum[tid>>6]=ls;
  __syncthreads();
  if (tid==0)
    lossPartial[r] = (wsum[0]+wsum[1]+wsum[2]+wsum[3]) * (1.0f/((float)NT*(float)DO));
}

__global__ __launch_bounds__(256) void k_lossreduce(const float* __restrict__ lp,
                                                    float* __restrict__ out)
{
  __shared__ double ws[4];
  double s=0.0;
  for (int i=threadIdx.x;i<NT;i+=256) s += (double)lp[i];
#pragma unroll
  for (int off=32; off>=1; off>>=1) s += __shfl_down(s, off);
  if ((threadIdx.x&63)==0) ws[threadIdx.x>>6]=s;
  __syncthreads();
  if (threadIdx.x==0) *out = (float)(ws[0]+ws[1]+ws[2]+ws[3]);
}

// ---------------- finalize h: zero + scatter ----------------
__global__ __launch_bounds__(256) void k_scatter(
    float* __restrict__ H, const int* __restrict__ candIdx, const float* __restrict__ candVal)
{
  const int r=blockIdx.x, tid=threadIdx.x;
  float* hr = H + (size_t)r*DH;
  const float4 z = {0.f,0.f,0.f,0.f};
#pragma unroll
  for (int i=0;i<16;i++) ((float4*)hr)[tid + i*256] = z;
  __syncthreads();
  if (tid<KSEL){
    float v = candVal[(size_t)r*KSEL+tid];
    hr[candIdx[(size_t)r*KSEL+tid]] = v>0.f ? v : 0.f;
  }
}

extern "C" void kernel_launch(void* const* d_in, const int* in_sizes, int n_in,
                              void* d_out, int out_size, void* d_ws, size_t ws_size,
                              hipStream_t stream)
{
  const float* X     = (const float*)d_in[0];
  const float* tgt   = (const float*)d_in[1];
  const float* Wenc  = (const float*)d_in[2];
  const float* benc  = (const float*)d_in[3];
  const float* Wdec  = (const float*)d_in[4];
  const float* bdec  = (const float*)d_in[5];
  const float* Wskip = (const float*)d_in[6];
  const float* bskip = (const float*)d_in[7];

  float* out     = (float*)d_out;
  float* outhat  = out;
  float* H       = out + (size_t)NT*DO;
  float* lossOut = out + (size_t)NT*DO + (size_t)NT*DH;

  // h-region scratch plan (dead until k_scatter):
  //   [0, 2^28)        : f16 pre-acts
  //   [2^28, ...)      : f16 copies of X, W_enc, W_skip, W_dec^T
  char* hb = (char*)H;
  unsigned short* P      = (unsigned short*)hb;
  char* U                = hb + (size_t)NT*DH*2;
  unsigned short* Xh     = (unsigned short*)U;
  unsigned short* Wench  = (unsigned short*)(U + (size_t)NT*DI*2);
  unsigned short* Wskiph = (unsigned short*)(U + (size_t)NT*DI*2 + (size_t)DH*DI*2);
  unsigned short* WdTh   = (unsigned short*)(U + (size_t)NT*DI*2 + (size_t)DH*DI*2 + (size_t)DO*DI*2);

  // ws: candidate lists must survive the h overwrite
  int*   candIdx    = (int*)d_ws;
  float* candVal    = (float*)((char*)d_ws + (size_t)NT*KSEL*4);
  float* lossPartial= (float*)((char*)d_ws + (size_t)NT*KSEL*8);

  k_cvt<<<NT*DI/8/256, 256, 0, stream>>>(X, Xh, NT*DI/8);
  k_cvt<<<DH*DI/8/256, 256, 0, stream>>>(Wenc, Wench, DH*DI/8);
  k_cvt<<<DO*DI/8/256, 256, 0, stream>>>(Wskip, Wskiph, DO*DI/8);
  k_transpose_cvt<<<dim3(DO/64, DH/64), 256, 0, stream>>>(Wdec, WdTh);

  k_gemm<true ><<<(NT/128)*(DH/128), 256, 0, stream>>>(Xh, Wench, benc, nullptr, (void*)P, DH, DI, DH/128);
  k_topk<<<NT, 256, 0, stream>>>(P, X, Wenc, benc, candIdx, candVal);
  k_gemm<false><<<(NT/128)*(DO/128), 256, 0, stream>>>(Xh, Wskiph, bdec, bskip, (void*)outhat, DO, DI, DO/128);
  k_decode<<<NT, 256, 0, stream>>>(outhat, WdTh, candIdx, candVal, tgt, lossPartial);
  k_lossreduce<<<1, 256, 0, stream>>>(lossPartial, lossOut);
  k_scatter<<<NT, 256, 0, stream>>>(H, candIdx, candVal);
}